// Round 17
// baseline (230.704 us; speedup 1.0000x reference)
//
#include <hip/hip_runtime.h>

// Scatter2Operator: B=8, N=4096, G=64, D0=D2=1024, H=16, Dh=64
//   k  = softmax_g(x2 @ Wk^T)            [B*N, H*G=1024]
//   P  = x0 @ Wp^T (fused into Qt blocks, never materialized)
//   Qt[b][d][h*64+g] = sum_dh P[b,g,h*64+dh] * Wo[d][h*64+dh]   [B,1024,1024]
//   out[b] = k[b] @ Qt[b]^T + bo          [B*N, 1024] f32

using bf16x8 = __attribute__((ext_vector_type(8))) __bf16;
using f32x4  = __attribute__((ext_vector_type(4))) float;

__device__ __forceinline__ unsigned short f2b(float f) {
  unsigned u = __float_as_uint(f);
  u += 0x7fffu + ((u >> 16) & 1u);   // RNE
  return (unsigned short)(u >> 16);
}

// One pass over the f32 inputs -> bf16 (segmented grid-stride).
__global__ void cvt_all(const float* __restrict__ x2, unsigned short* __restrict__ x2b, int n0,
                        const float* __restrict__ x0, unsigned short* __restrict__ x0b, int n1,
                        const float* __restrict__ Wk, unsigned short* __restrict__ Wkb, int n2,
                        const float* __restrict__ Wp, unsigned short* __restrict__ Wpb, int n3,
                        const float* __restrict__ Wo, unsigned short* __restrict__ Wob, int n4)
{
  const int ntot = n0 + n1 + n2 + n3 + n4;
  int i = blockIdx.x * blockDim.x + threadIdx.x;
  const int stride = gridDim.x * blockDim.x;
  for (; i < ntot; i += stride) {
    const float* src; unsigned short* dst; int j = i;
    if (j < n0) { src = x2; dst = x2b; }
    else if ((j -= n0) < n1) { src = x0; dst = x0b; }
    else if ((j -= n1) < n2) { src = Wk; dst = Wkb; }
    else if ((j -= n2) < n3) { src = Wp; dst = Wpb; }
    else { j -= n3; src = Wo; dst = Wob; }
    float4 v = reinterpret_cast<const float4*>(src)[j];
    ushort4 o;
    o.x = f2b(v.x); o.y = f2b(v.y); o.z = f2b(v.z); o.w = f2b(v.w);
    reinterpret_cast<ushort4*>(dst)[j] = o;
  }
}

#define GLOAD_LDS(gsrc, ldst) __builtin_amdgcn_global_load_lds(                 \
    (const __attribute__((address_space(1))) unsigned int*)(gsrc),              \
    (__attribute__((address_space(3))) unsigned int*)(ldst), 16, 0, 0)

// Staging load opaque to compiler alias tracking: raw M0 + global_load_lds.
__device__ __forceinline__ void glds16(const unsigned short* g, unsigned ldsoff) {
  asm volatile("s_mov_b32 m0, %0\n\t"
               "global_load_lds_dwordx4 %1, off"
               :: "s"(ldsoff), "v"(g) : "memory");
}

#define BARRIER() __builtin_amdgcn_s_barrier()
#define VMC8()   asm volatile("s_waitcnt vmcnt(8)" ::: "memory")
#define VMC4()   asm volatile("s_waitcnt vmcnt(4)" ::: "memory")
#define VMC0()   asm volatile("s_waitcnt vmcnt(0)" ::: "memory")
#define LGKM0()  asm volatile("s_waitcnt lgkmcnt(0)" ::: "memory")

// ---------------- Fused P + Qt kernel (verified R14) ----------------
__launch_bounds__(256)
__global__ void qtp(const unsigned short* __restrict__ x0b,
                    const unsigned short* __restrict__ Wpb,
                    const unsigned short* __restrict__ Wob,
                    unsigned short* __restrict__ Qtb)
{
  __shared__ __align__(16) unsigned short Pl[64 * 72];     // 9 KB
  __shared__ __align__(16) unsigned short work[16384];     // 32 KB

  const int bx = blockIdx.x;
  const int z  = blockIdx.z;
  const int b  = z >> 4, h = z & 15;

  const int tid  = threadIdx.x;
  const int lane = tid & 63;
  const int wid  = tid >> 6;
  const int lr   = lane & 15;
  const int hi   = lane >> 4;

  const int wr1 = (wid >> 1) * 32, wc1 = (wid & 1) * 32;
  f32x4 acc1[2][2] = {};

  int srow[2], skc[2];
#pragma unroll
  for (int j = 0; j < 2; ++j) {
    int i = j * 256 + tid;
    srow[j] = i >> 3;
    skc[j]  = ((i & 7) ^ (srow[j] & 7)) * 8;
  }
  const unsigned short* aSrc = x0b + (long)b * 65536;
  const unsigned short* bSrc = Wpb + (long)h * 64 * 1024;

  for (int kt = 0; kt < 1024; kt += 64) {
    __syncthreads();
#pragma unroll
    for (int j = 0; j < 2; ++j) {
      int i = j * 256 + tid;
      GLOAD_LDS(aSrc + (long)srow[j] * 1024 + kt + skc[j], &work[i * 8]);
      GLOAD_LDS(bSrc + (long)srow[j] * 1024 + kt + skc[j], &work[4096 + i * 8]);
    }
    __syncthreads();

    bf16x8 af[2][2], bf[2][2];
#pragma unroll
    for (int m = 0; m < 2; ++m) {
      const int rowA = wr1 + m * 16 + lr;
      const int rowB = wc1 + m * 16 + lr;
#pragma unroll
      for (int ks = 0; ks < 2; ++ks) {
        const int slotA = ((ks * 4 + hi) ^ (rowA & 7)) * 8;
        const int slotB = ((ks * 4 + hi) ^ (rowB & 7)) * 8;
        af[m][ks] = *(const bf16x8*)&work[rowA * 64 + slotA];
        bf[m][ks] = *(const bf16x8*)&work[4096 + rowB * 64 + slotB];
      }
    }
#pragma unroll
    for (int ks = 0; ks < 2; ++ks)
#pragma unroll
      for (int m = 0; m < 2; ++m)
#pragma unroll
        for (int n = 0; n < 2; ++n)
          acc1[m][n] = __builtin_amdgcn_mfma_f32_16x16x32_bf16(
              af[m][ks], bf[n][ks], acc1[m][n], 0, 0, 0);
  }

#pragma unroll
  for (int m = 0; m < 2; ++m)
#pragma unroll
    for (int r = 0; r < 4; ++r) {
      const int row = wr1 + m * 16 + hi * 4 + r;
#pragma unroll
      for (int n = 0; n < 2; ++n)
        Pl[row * 72 + wc1 + n * 16 + lr] = f2b(acc1[m][n][r]);
    }
  __syncthreads();

  const unsigned short* wSrc = Wob + (long)bx * 256 * 1024 + h * 64;
#pragma unroll
  for (int j = 0; j < 8; ++j) {
    int i = j * 256 + tid;
    int row = i >> 3;
    int kc  = ((i & 7) ^ (row & 7)) * 8;
    GLOAD_LDS(wSrc + (long)row * 1024 + kc, &work[i * 8]);
  }
  __syncthreads();

  const int wr2 = wid * 64;
  f32x4 acc2[4][4] = {};
  bf16x8 af2[4][2], bf2[4][2];
#pragma unroll
  for (int m = 0; m < 4; ++m) {
    const int rowA = wr2 + m * 16 + lr;
#pragma unroll
    for (int ks = 0; ks < 2; ++ks) {
      const int slotA = ((ks * 4 + hi) ^ (rowA & 7)) * 8;
      af2[m][ks] = *(const bf16x8*)&work[rowA * 64 + slotA];
    }
  }
#pragma unroll
  for (int n = 0; n < 4; ++n) {
    const int rowB = n * 16 + lr;
#pragma unroll
    for (int ks = 0; ks < 2; ++ks)
      bf2[n][ks] = *(const bf16x8*)&Pl[rowB * 72 + ks * 32 + hi * 8];
  }
#pragma unroll
  for (int ks = 0; ks < 2; ++ks)
#pragma unroll
    for (int m = 0; m < 4; ++m)
#pragma unroll
      for (int n = 0; n < 4; ++n)
        acc2[m][n] = __builtin_amdgcn_mfma_f32_16x16x32_bf16(
            af2[m][ks], bf2[n][ks], acc2[m][n], 0, 0, 0);

  unsigned short* Cq = Qtb + (long)b * 1048576 + h * 64;
#pragma unroll
  for (int n = 0; n < 4; ++n) {
    const int col = n * 16 + lr;
#pragma unroll
    for (int m = 0; m < 4; ++m)
#pragma unroll
      for (int r = 0; r < 4; ++r) {
        const int row = bx * 256 + wr2 + m * 16 + hi * 4 + r;
        Cq[(long)row * 1024 + col] = f2b(acc2[m][n][r]);
      }
  }
}

// ---------------- 256^2 4-phase ONE-AHEAD kernel (R17 = R16 + compile fix) ---
// BM=BN=256, BK=64, 8 waves (2M x 4N), per-wave 128x64. LDS 128KB
// [A0|B0|A1|B1]; XOR swizzle; asm gload_lds. Every mma's operands were
// ds_read >=1 phase earlier (counted lgkm waits find data arrived ->
// LDS port drains DURING mma, not before it). LDS bases computed by
// integer arithmetic (runtime buf CANNOT index a pointer array — R16
// compile failure: addrspacecast static initializer).
template<int EPI, int BATCHED>
__launch_bounds__(512)
__global__ void gemm256(const unsigned short* __restrict__ A,
                        const unsigned short* __restrict__ B,
                        void* __restrict__ Cv,
                        const float* __restrict__ bias,
                        int K, long sA, long sB, long sC)
{
  extern __shared__ __align__(16) char smem[];

  const int tid  = threadIdx.x;
  const int lane = tid & 63, wid = tid >> 6;
  const int wm = wid >> 2, wn = wid & 3;
  const int lr = lane & 15, hi = lane >> 4;
  const int swz  = (lane & 7) << 4;
  const int prow = lane >> 3;
  const int pxor = ((lane & 7) ^ prow) * 8;

  int bx, by; long abase = 0, bbase = 0, cbase = 0;
  if (BATCHED) {
    const int bid = blockIdx.x;
    const int z = bid & 7, idx = bid >> 3;
    bx = idx & 15; by = idx >> 4;
    abase = (long)z * sA; bbase = (long)z * sB; cbase = (long)z * sC;
  } else {
    const int bid = blockIdx.x;
    const int lin = (bid & 7) * 64 + (bid >> 3);   // XCD-bijective
    bx = lin >> 2; by = lin & 3;
  }
  const int brow = bx * 256, bcol = by * 256;

  const unsigned short* __restrict__ Ab = A + abase;
  const unsigned short* __restrict__ Bb = B + bbase;

  const unsigned ldsbase =
      __builtin_amdgcn_readfirstlane((unsigned)(unsigned long long)smem);

  const long ldaL = 1024, ldbL = 1024, ldcL = 1024;

  auto stageA = [&](int buf, int h, int kt) {
    const unsigned short* s = Ab + (long)(brow + h * 128 + wid * 8 + prow) * ldaL + kt + pxor;
    unsigned d = ldsbase + (unsigned)(buf * 65536 + h * 16384 + wid * 1024);
    glds16(s, __builtin_amdgcn_readfirstlane(d));
    glds16(s + 64 * ldaL, __builtin_amdgcn_readfirstlane(d + 8192u));
  };
  auto stageB = [&](int buf, int h, int kt) {
    const unsigned short* s = Bb + (long)(bcol + h * 128 + wid * 8 + prow) * ldbL + kt + pxor;
    unsigned d = ldsbase + (unsigned)(32768 + buf * 65536 + h * 16384 + wid * 1024);
    glds16(s, __builtin_amdgcn_readfirstlane(d));
    glds16(s + 64 * ldbL, __builtin_amdgcn_readfirstlane(d + 8192u));
  };

  // LDS read bases by arithmetic (runtime buf safe).
  auto ldsAp = [&](int buf) {
    return (const unsigned short*)(smem + buf * 65536);
  };
  auto ldsBp = [&](int buf) {
    return (const unsigned short*)(smem + 32768 + buf * 65536);
  };

  // Frag sets (24 total = 96 VGPR): afA/afB A-half ping-pong; blo/bhi single.
  bf16x8 afA[4][2], afB[4][2], blo[2][2], bhi[2][2];

  auto ldAx = [&](int buf, int mh, bf16x8 (&dst)[4][2]) {
    const unsigned short* base = ldsAp(buf);
#pragma unroll
    for (int mi = 0; mi < 4; ++mi) {
      const int row = wm * 128 + mh * 64 + mi * 16 + lr;
#pragma unroll
      for (int ks = 0; ks < 2; ++ks) {
        const int cb = (ks * 64 + hi * 16) ^ swz;
        dst[mi][ks] = *(const bf16x8*)(base + row * 64 + (cb >> 1));
      }
    }
  };
  auto ldBlo_ = [&](int buf) {
    const unsigned short* base = ldsBp(buf);
#pragma unroll
    for (int ni = 0; ni < 2; ++ni) {
      const int row = wn * 64 + ni * 16 + lr;
#pragma unroll
      for (int ks = 0; ks < 2; ++ks) {
        const int cb = (ks * 64 + hi * 16) ^ swz;
        blo[ni][ks] = *(const bf16x8*)(base + row * 64 + (cb >> 1));
      }
    }
  };
  auto ldBhi_ = [&](int buf) {
    const unsigned short* base = ldsBp(buf);
#pragma unroll
    for (int ni = 0; ni < 2; ++ni) {
      const int row = wn * 64 + 32 + ni * 16 + lr;
#pragma unroll
      for (int ks = 0; ks < 2; ++ks) {
        const int cb = (ks * 64 + hi * 16) ^ swz;
        bhi[ni][ks] = *(const bf16x8*)(base + row * 64 + (cb >> 1));
      }
    }
  };

  f32x4 acc[8][4] = {};
  auto mmaH = [&](bf16x8 (&a)[4][2], bf16x8 (&b)[2][2], int mh, int nh) {
    __builtin_amdgcn_s_setprio(1);
#pragma unroll
    for (int ks = 0; ks < 2; ++ks)
#pragma unroll
      for (int mi = 0; mi < 4; ++mi)
#pragma unroll
        for (int ni = 0; ni < 2; ++ni)
          acc[mh * 4 + mi][nh * 2 + ni] = __builtin_amdgcn_mfma_f32_16x16x32_bf16(
              a[mi][ks], b[ni][ks], acc[mh * 4 + mi][nh * 2 + ni], 0, 0, 0);
    __builtin_amdgcn_s_setprio(0);
  };

  // Prologue: stage T0 (8 loads) then T1 (8). vmcnt(8) => T0 landed.
  stageA(0, 0, 0); stageA(0, 1, 0); stageB(0, 0, 0); stageB(0, 1, 0);
  stageA(1, 0, 64); stageA(1, 1, 64); stageB(1, 0, 64); stageB(1, 1, 64);
  VMC8(); BARRIER();
  ldAx(0, 0, afA); ldBlo_(0);   // pre-reads for t=0 ph0

  const int NT = K >> 6;   // 16 K-tiles
#pragma unroll 1
  for (int t = 0; t < NT; ++t) {
    const int buf = t & 1, nbuf = buf ^ 1;
    int ktn = (t + 2) * 64; if (ktn >= K) ktn -= K;   // wrap: garbage, never mma'd

    // ph0: read B-hi(buf_t) (buf_t landed: prologue VMC8 / prev ph3 VMC4).
    VMC8(); ldBhi_(buf);
    BARRIER(); mmaH(afA, blo, 0, 0); BARRIER();
    // ph1: read A-h1(buf_t); LGKM0 before barrier closes the WAR window
    //      (afB reads must complete before other waves' ph2 stage lands).
    ldAx(buf, 1, afB);
    BARRIER(); mmaH(afA, bhi, 0, 1); LGKM0(); BARRIER();
    // ph2: stage A(t+2) -> buf_t (A reads of buf_t finished ph1).
    stageA(buf, 0, ktn); stageA(buf, 1, ktn);
    BARRIER(); mmaH(afB, blo, 1, 0); BARRIER();
    // ph3: vmcnt(4) => T(t+1) landed (4 newer = A(t+2)); pre-read
    //      A-h0 + B-lo of buf_{t+1}; stage B(t+2) -> buf_t.
    VMC4(); ldAx(nbuf, 0, afA); ldBlo_(nbuf);
    stageB(buf, 0, ktn); stageB(buf, 1, ktn);
    BARRIER(); mmaH(afB, bhi, 1, 1); BARRIER();
  }
  VMC0();   // drain wrapped garbage loads before LDS dealloc

  const int rowb = brow + wm * 128 + hi * 4;
  const int colb = bcol + wn * 64 + lr;

  if (EPI == 2) {
    unsigned short* C = (unsigned short*)Cv + cbase;
#pragma unroll
    for (int m = 0; m < 8; ++m) {
#pragma unroll
      for (int r = 0; r < 4; ++r) {
        float v0 = acc[m][0][r], v1 = acc[m][1][r], v2 = acc[m][2][r], v3 = acc[m][3][r];
        float mx = fmaxf(fmaxf(v0, v1), fmaxf(v2, v3));
        mx = fmaxf(mx, __shfl_xor(mx, 1));
        mx = fmaxf(mx, __shfl_xor(mx, 2));
        mx = fmaxf(mx, __shfl_xor(mx, 4));
        mx = fmaxf(mx, __shfl_xor(mx, 8));
        float e0 = __expf(v0 - mx), e1 = __expf(v1 - mx);
        float e2 = __expf(v2 - mx), e3 = __expf(v3 - mx);
        float s = e0 + e1 + e2 + e3;
        s += __shfl_xor(s, 1);
        s += __shfl_xor(s, 2);
        s += __shfl_xor(s, 4);
        s += __shfl_xor(s, 8);
        float inv = 1.0f / s;
        unsigned short* cp = C + (long)(rowb + m * 16 + r) * ldcL + colb;
        cp[0]  = f2b(e0 * inv);
        cp[16] = f2b(e1 * inv);
        cp[32] = f2b(e2 * inv);
        cp[48] = f2b(e3 * inv);
      }
    }
  } else {
    float* C = (float*)Cv + cbase;
#pragma unroll
    for (int n = 0; n < 4; ++n) {
      const int col = colb + n * 16;
      const float bv = bias[col];
#pragma unroll
      for (int m = 0; m < 8; ++m)
#pragma unroll
        for (int r = 0; r < 4; ++r)
          C[(long)(rowb + m * 16 + r) * ldcL + col] = acc[m][n][r] + bv;
    }
  }
}

extern "C" void kernel_launch(void* const* d_in, const int* in_sizes, int n_in,
                              void* d_out, int out_size, void* d_ws, size_t ws_size,
                              hipStream_t stream) {
  (void)in_sizes; (void)n_in; (void)out_size; (void)ws_size;
  const float* x0 = (const float*)d_in[0];
  const float* x2 = (const float*)d_in[1];
  const float* Wk = (const float*)d_in[2];
  const float* Wp = (const float*)d_in[3];
  const float* Wo = (const float*)d_in[4];
  const float* bo = (const float*)d_in[5];
  float* out = (float*)d_out;

  const long Bz = 8, Nn = 4096, Gg = 64, Dd = 1024;
  const long MN = Bz * Nn;  // 32768

  char* ws = (char*)d_ws;
  size_t off = 0;
  auto alloc = [&](size_t bytes) {
    size_t cur = off;
    off = (cur + bytes + 255) & ~(size_t)255;
    return (unsigned short*)(ws + cur);
  };
  unsigned short* x2b = alloc(MN * Dd * 2);       // 67 MB
  unsigned short* kb  = alloc(MN * Dd * 2);       // 67 MB
  unsigned short* Wkb = alloc(Dd * Dd * 2);
  unsigned short* Wpb = alloc(Dd * Dd * 2);
  unsigned short* Wob = alloc(Dd * Dd * 2);
  unsigned short* x0b = alloc(Bz * Gg * Dd * 2);
  unsigned short* Qtb = alloc(Bz * Dd * Dd * 2);  // 16.8 MB

  (void)hipFuncSetAttribute(reinterpret_cast<const void*>(gemm256<2, 0>),
                            hipFuncAttributeMaxDynamicSharedMemorySize, 131072);
  (void)hipFuncSetAttribute(reinterpret_cast<const void*>(gemm256<1, 1>),
                            hipFuncAttributeMaxDynamicSharedMemorySize, 131072);

  // Single cvt pass over all five f32 inputs.
  cvt_all<<<dim3(4096), dim3(256), 0, stream>>>(
      x2, x2b, (int)(MN * Dd / 4),
      x0, x0b, (int)(Bz * Gg * Dd / 4),
      Wk, Wkb, (int)(Dd * Dd / 4),
      Wp, Wpb, (int)(Dd * Dd / 4),
      Wo, Wob, (int)(Dd * Dd / 4));

  // GEMM1: kb = softmax_per_head(x2b @ Wkb^T), 512 blocks.
  gemm256<2, 0><<<dim3(512, 1, 1), dim3(512), 131072, stream>>>(
      x2b, Wkb, kb, nullptr, 1024, 0, 0, 0);

  // Fused P+Qt.
  qtp<<<dim3(4, 1, 128), dim3(256), 0, stream>>>(x0b, Wpb, Wob, Qtb);

  // out[b] = kb[b] @ Qtb[b]^T + bo, one batch per XCD.
  gemm256<1, 1><<<dim3(512, 1, 1), dim3(512), 131072, stream>>>(
      kb, Qtb, (void*)out, bo, 1024,
      (long)4096 * 1024, (long)1024 * 1024, (long)4096 * 1024);
}

// Round 18
// 217.798 us; speedup vs baseline: 1.0593x; 1.0593x over previous
//
#include <hip/hip_runtime.h>

// Scatter2Operator: B=8, N=4096, G=64, D0=D2=1024, H=16, Dh=64
//   k  = softmax_g(x2 @ Wk^T)            [B*N, H*G=1024]
//   P  = x0 @ Wp^T (fused into Qt blocks, never materialized)
//   Qt[b][d][h*64+g] = sum_dh P[b,g,h*64+dh] * Wo[d][h*64+dh]   [B,1024,1024]
//   out[b] = k[b] @ Qt[b]^T + bo          [B*N, 1024] f32
//
// Final configuration (R15-best): single-pass cvt (HBM-roofline, 33us),
// gemm256 balanced read-once 8-phase (86us, 32% MfmaUtil — best of 11
// schedule variants R2-R17), fused P+Qt (5us), batched GEMM2 (88us).

using bf16x8 = __attribute__((ext_vector_type(8))) __bf16;
using f32x4  = __attribute__((ext_vector_type(4))) float;

__device__ __forceinline__ unsigned short f2b(float f) {
  unsigned u = __float_as_uint(f);
  u += 0x7fffu + ((u >> 16) & 1u);   // RNE
  return (unsigned short)(u >> 16);
}

// One pass over the f32 inputs -> bf16 (segmented grid-stride).
__global__ void cvt_all(const float* __restrict__ x2, unsigned short* __restrict__ x2b, int n0,
                        const float* __restrict__ x0, unsigned short* __restrict__ x0b, int n1,
                        const float* __restrict__ Wk, unsigned short* __restrict__ Wkb, int n2,
                        const float* __restrict__ Wp, unsigned short* __restrict__ Wpb, int n3,
                        const float* __restrict__ Wo, unsigned short* __restrict__ Wob, int n4)
{
  const int ntot = n0 + n1 + n2 + n3 + n4;
  int i = blockIdx.x * blockDim.x + threadIdx.x;
  const int stride = gridDim.x * blockDim.x;
  for (; i < ntot; i += stride) {
    const float* src; unsigned short* dst; int j = i;
    if (j < n0) { src = x2; dst = x2b; }
    else if ((j -= n0) < n1) { src = x0; dst = x0b; }
    else if ((j -= n1) < n2) { src = Wk; dst = Wkb; }
    else if ((j -= n2) < n3) { src = Wp; dst = Wpb; }
    else { j -= n3; src = Wo; dst = Wob; }
    float4 v = reinterpret_cast<const float4*>(src)[j];
    ushort4 o;
    o.x = f2b(v.x); o.y = f2b(v.y); o.z = f2b(v.z); o.w = f2b(v.w);
    reinterpret_cast<ushort4*>(dst)[j] = o;
  }
}

#define GLOAD_LDS(gsrc, ldst) __builtin_amdgcn_global_load_lds(                 \
    (const __attribute__((address_space(1))) unsigned int*)(gsrc),              \
    (__attribute__((address_space(3))) unsigned int*)(ldst), 16, 0, 0)

// Staging load opaque to the compiler's alias tracking (no conservative
// vmcnt(0) drains): raw M0 + global_load_lds_dwordx4. LDS dest = M0 + lane*16.
__device__ __forceinline__ void glds16(const unsigned short* g, unsigned ldsoff) {
  asm volatile("s_mov_b32 m0, %0\n\t"
               "global_load_lds_dwordx4 %1, off"
               :: "s"(ldsoff), "v"(g) : "memory");
}

#define BARRIER() __builtin_amdgcn_s_barrier()
#define VMC4()   asm volatile("s_waitcnt vmcnt(4)" ::: "memory")
#define VMC0()   asm volatile("s_waitcnt vmcnt(0)" ::: "memory")

// ---------------- Fused P + Qt kernel (verified R14) ----------------
__launch_bounds__(256)
__global__ void qtp(const unsigned short* __restrict__ x0b,
                    const unsigned short* __restrict__ Wpb,
                    const unsigned short* __restrict__ Wob,
                    unsigned short* __restrict__ Qtb)
{
  __shared__ __align__(16) unsigned short Pl[64 * 72];     // 9 KB
  __shared__ __align__(16) unsigned short work[16384];     // 32 KB

  const int bx = blockIdx.x;
  const int z  = blockIdx.z;
  const int b  = z >> 4, h = z & 15;

  const int tid  = threadIdx.x;
  const int lane = tid & 63;
  const int wid  = tid >> 6;
  const int lr   = lane & 15;
  const int hi   = lane >> 4;

  // stage 1: Pl = x0[b] @ Wp[h]^T, 64x64, K=1024, BK=64
  const int wr1 = (wid >> 1) * 32, wc1 = (wid & 1) * 32;
  f32x4 acc1[2][2] = {};

  int srow[2], skc[2];
#pragma unroll
  for (int j = 0; j < 2; ++j) {
    int i = j * 256 + tid;
    srow[j] = i >> 3;
    skc[j]  = ((i & 7) ^ (srow[j] & 7)) * 8;
  }
  const unsigned short* aSrc = x0b + (long)b * 65536;
  const unsigned short* bSrc = Wpb + (long)h * 64 * 1024;

  for (int kt = 0; kt < 1024; kt += 64) {
    __syncthreads();
#pragma unroll
    for (int j = 0; j < 2; ++j) {
      int i = j * 256 + tid;
      GLOAD_LDS(aSrc + (long)srow[j] * 1024 + kt + skc[j], &work[i * 8]);
      GLOAD_LDS(bSrc + (long)srow[j] * 1024 + kt + skc[j], &work[4096 + i * 8]);
    }
    __syncthreads();

    bf16x8 af[2][2], bf[2][2];
#pragma unroll
    for (int m = 0; m < 2; ++m) {
      const int rowA = wr1 + m * 16 + lr;
      const int rowB = wc1 + m * 16 + lr;
#pragma unroll
      for (int ks = 0; ks < 2; ++ks) {
        const int slotA = ((ks * 4 + hi) ^ (rowA & 7)) * 8;
        const int slotB = ((ks * 4 + hi) ^ (rowB & 7)) * 8;
        af[m][ks] = *(const bf16x8*)&work[rowA * 64 + slotA];
        bf[m][ks] = *(const bf16x8*)&work[4096 + rowB * 64 + slotB];
      }
    }
#pragma unroll
    for (int ks = 0; ks < 2; ++ks)
#pragma unroll
      for (int m = 0; m < 2; ++m)
#pragma unroll
        for (int n = 0; n < 2; ++n)
          acc1[m][n] = __builtin_amdgcn_mfma_f32_16x16x32_bf16(
              af[m][ks], bf[n][ks], acc1[m][n], 0, 0, 0);
  }

#pragma unroll
  for (int m = 0; m < 2; ++m)
#pragma unroll
    for (int r = 0; r < 4; ++r) {
      const int row = wr1 + m * 16 + hi * 4 + r;
#pragma unroll
      for (int n = 0; n < 2; ++n)
        Pl[row * 72 + wc1 + n * 16 + lr] = f2b(acc1[m][n][r]);
    }
  __syncthreads();

  // stage 2: Qt tile = Wo[bx*256..][h*64..] @ Pl^T, K=64
  const unsigned short* wSrc = Wob + (long)bx * 256 * 1024 + h * 64;
#pragma unroll
  for (int j = 0; j < 8; ++j) {
    int i = j * 256 + tid;
    int row = i >> 3;
    int kc  = ((i & 7) ^ (row & 7)) * 8;
    GLOAD_LDS(wSrc + (long)row * 1024 + kc, &work[i * 8]);
  }
  __syncthreads();

  const int wr2 = wid * 64;
  f32x4 acc2[4][4] = {};
  bf16x8 af2[4][2], bf2[4][2];
#pragma unroll
  for (int m = 0; m < 4; ++m) {
    const int rowA = wr2 + m * 16 + lr;
#pragma unroll
    for (int ks = 0; ks < 2; ++ks) {
      const int slotA = ((ks * 4 + hi) ^ (rowA & 7)) * 8;
      af2[m][ks] = *(const bf16x8*)&work[rowA * 64 + slotA];
    }
  }
#pragma unroll
  for (int n = 0; n < 4; ++n) {
    const int rowB = n * 16 + lr;
#pragma unroll
    for (int ks = 0; ks < 2; ++ks)
      bf2[n][ks] = *(const bf16x8*)&Pl[rowB * 72 + ks * 32 + hi * 8];
  }
#pragma unroll
  for (int ks = 0; ks < 2; ++ks)
#pragma unroll
    for (int m = 0; m < 4; ++m)
#pragma unroll
      for (int n = 0; n < 4; ++n)
        acc2[m][n] = __builtin_amdgcn_mfma_f32_16x16x32_bf16(
            af2[m][ks], bf2[n][ks], acc2[m][n], 0, 0, 0);

  unsigned short* Cq = Qtb + (long)b * 1048576 + h * 64;
#pragma unroll
  for (int n = 0; n < 4; ++n) {
    const int col = n * 16 + lr;
#pragma unroll
    for (int m = 0; m < 4; ++m)
#pragma unroll
      for (int r = 0; r < 4; ++r) {
        const int row = bx * 256 + wr2 + m * 16 + hi * 4 + r;
        Cq[(long)row * 1024 + col] = f2b(acc2[m][n][r]);
      }
  }
}

// ---------------- 256^2 8-phase kernel — R15 balanced read-once --------------
// BM=BN=256, BK=64, 512 threads = 8 waves (2M x 4N), per-wave out 128x64.
// LDS 128KB [A0|B0|A1|B1]; XOR swizzle byte^=(row&7)<<4; asm global_load_lds;
// counted vmcnt(4) at ph4/ph8; ks-outer MFMA; no lgkm pinning.
// BALANCED 8/4/8/4 ds_reads per phase (read-once, 24/K-tile): af[4][2] shared
// between A-halves (disjoint live ranges), bloA/bloB ping-pong (pre-read one
// phase ahead AFTER the VMC4 that guarantees its buffer landed), bhi single.
// EPI: 1 = f32+bias, 2 = softmax bf16. BATCHED: 0 = XCD swizzle, 1 = z=bid&7.
template<int EPI, int BATCHED>
__launch_bounds__(512)
__global__ void gemm256(const unsigned short* __restrict__ A,
                        const unsigned short* __restrict__ B,
                        void* __restrict__ Cv,
                        const float* __restrict__ bias,
                        int K, long sA, long sB, long sC)
{
  extern __shared__ __align__(16) char smem[];

  const int tid  = threadIdx.x;
  const int lane = tid & 63, wid = tid >> 6;
  const int wm = wid >> 2, wn = wid & 3;
  const int lr = lane & 15, hi = lane >> 4;
  const int swz  = (lane & 7) << 4;
  const int prow = lane >> 3;
  const int pxor = ((lane & 7) ^ prow) * 8;

  int bx, by; long abase = 0, bbase = 0, cbase = 0;
  if (BATCHED) {
    const int bid = blockIdx.x;
    const int z = bid & 7, idx = bid >> 3;
    bx = idx & 15; by = idx >> 4;
    abase = (long)z * sA; bbase = (long)z * sB; cbase = (long)z * sC;
  } else {
    const int bid = blockIdx.x;
    const int lin = (bid & 7) * 64 + (bid >> 3);   // XCD-bijective
    bx = lin >> 2; by = lin & 3;
  }
  const int brow = bx * 256, bcol = by * 256;

  const unsigned short* __restrict__ Ab = A + abase;
  const unsigned short* __restrict__ Bb = B + bbase;

  unsigned short* ldsA[2] = { (unsigned short*)(smem),
                              (unsigned short*)(smem + 65536) };
  unsigned short* ldsB[2] = { (unsigned short*)(smem + 32768),
                              (unsigned short*)(smem + 98304) };
  const unsigned ldsbase =
      __builtin_amdgcn_readfirstlane((unsigned)(unsigned long long)smem);

  const long ldaL = 1024, ldbL = 1024, ldcL = 1024;

  auto stageA = [&](int buf, int h, int kt) {
    const unsigned short* s = Ab + (long)(brow + h * 128 + wid * 8 + prow) * ldaL + kt + pxor;
    unsigned d = ldsbase + (unsigned)(buf * 65536 + h * 16384 + wid * 1024);
    glds16(s, __builtin_amdgcn_readfirstlane(d));
    glds16(s + 64 * ldaL, __builtin_amdgcn_readfirstlane(d + 8192u));
  };
  auto stageB = [&](int buf, int h, int kt) {
    const unsigned short* s = Bb + (long)(bcol + h * 128 + wid * 8 + prow) * ldbL + kt + pxor;
    unsigned d = ldsbase + (unsigned)(32768 + buf * 65536 + h * 16384 + wid * 1024);
    glds16(s, __builtin_amdgcn_readfirstlane(d));
    glds16(s + 64 * ldbL, __builtin_amdgcn_readfirstlane(d + 8192u));
  };

  // Frag sets: af shared A-half; bloA/bloB ping-pong; bhi single.
  bf16x8 af[4][2], bloA[2][2], bloB[2][2], bhi[2][2];

  auto ldA_ = [&](int buf, int mh) {
    const unsigned short* base = ldsA[buf];
#pragma unroll
    for (int mi = 0; mi < 4; ++mi) {
      const int row = wm * 128 + mh * 64 + mi * 16 + lr;
#pragma unroll
      for (int ks = 0; ks < 2; ++ks) {
        const int cb = (ks * 64 + hi * 16) ^ swz;
        af[mi][ks] = *(const bf16x8*)(base + row * 64 + (cb >> 1));
      }
    }
  };
  auto ldBlo = [&](int buf, bf16x8 (&dst)[2][2]) {
    const unsigned short* base = ldsB[buf];
#pragma unroll
    for (int ni = 0; ni < 2; ++ni) {
      const int row = wn * 64 + ni * 16 + lr;
#pragma unroll
      for (int ks = 0; ks < 2; ++ks) {
        const int cb = (ks * 64 + hi * 16) ^ swz;
        dst[ni][ks] = *(const bf16x8*)(base + row * 64 + (cb >> 1));
      }
    }
  };
  auto ldBhi = [&](int buf) {
    const unsigned short* base = ldsB[buf];
#pragma unroll
    for (int ni = 0; ni < 2; ++ni) {
      const int row = wn * 64 + 32 + ni * 16 + lr;
#pragma unroll
      for (int ks = 0; ks < 2; ++ks) {
        const int cb = (ks * 64 + hi * 16) ^ swz;
        bhi[ni][ks] = *(const bf16x8*)(base + row * 64 + (cb >> 1));
      }
    }
  };

  f32x4 acc[8][4] = {};
  auto mmaH = [&](bf16x8 (&b)[2][2], int mh, int nh) {
    __builtin_amdgcn_s_setprio(1);
#pragma unroll
    for (int ks = 0; ks < 2; ++ks)
#pragma unroll
      for (int mi = 0; mi < 4; ++mi)
#pragma unroll
        for (int ni = 0; ni < 2; ++ni)
          acc[mh * 4 + mi][nh * 2 + ni] = __builtin_amdgcn_mfma_f32_16x16x32_bf16(
              af[mi][ks], b[ni][ks], acc[mh * 4 + mi][nh * 2 + ni], 0, 0, 0);
    __builtin_amdgcn_s_setprio(0);
  };

  // Prologue: buf0 <- T0 (B,A); buf1 <- B(T1). Drain to 4 (buf0 complete),
  // then pre-read B-lo(buf0).
  stageB(0, 0, 0); stageB(0, 1, 0); stageA(0, 0, 0); stageA(0, 1, 0);
  stageB(1, 0, 64); stageB(1, 1, 64);
  VMC4(); BARRIER();
  ldBlo(0, bloA);

  const int NI = K >> 7;   // 2 K-tiles per iteration
#pragma unroll 1
  for (int i = 0; i < NI; ++i) {
    const int kt1 = i * 128 + 64;
    int kt2 = i * 128 + 128; if (kt2 >= K) kt2 -= K;   // wrap: garbage, never MFMA'd
    int kt3 = i * 128 + 192; if (kt3 >= K) kt3 -= K;

    // ph1 [8 rd]: A-h0(buf0); stage A(T1)-h0.
    ldA_(0, 0); stageA(1, 0, kt1);
    BARRIER(); mmaH(bloA, 0, 0); BARRIER();
    // ph2 [4 rd]: B-hi(buf0); stage A(T1)-h1.
    ldBhi(0); stageA(1, 1, kt1);
    BARRIER(); mmaH(bhi, 0, 1); BARRIER();
    // ph3 [8 rd]: A-h1(buf0); stage B(T2)-h0 (buf0-B reads done ph2).
    ldA_(0, 1); stageB(0, 0, kt2);
    BARRIER(); mmaH(bloA, 1, 0); BARRIER();
    // ph4 [4 rd]: stage B(T2)-h1; VMC4 (T1 A+B landed); pre-read B-lo(buf1).
    stageB(0, 1, kt2); VMC4(); ldBlo(1, bloB);
    BARRIER(); mmaH(bhi, 1, 1); BARRIER();
    // ph5 [8 rd]: A-h0(buf1); stage A(T2)-h0 (buf0-A reads done ph3).
    ldA_(1, 0); stageA(0, 0, kt2);
    BARRIER(); mmaH(bloB, 0, 0); BARRIER();
    // ph6 [4 rd]: B-hi(buf1); stage A(T2)-h1.
    ldBhi(1); stageA(0, 1, kt2);
    BARRIER(); mmaH(bhi, 0, 1); BARRIER();
    // ph7 [8 rd]: A-h1(buf1); stage B(T3)-h0 (buf1-B reads done ph6).
    ldA_(1, 1); stageB(1, 0, kt3);
    BARRIER(); mmaH(bloB, 1, 0); BARRIER();
    // ph8 [4 rd]: stage B(T3)-h1; VMC4 (T2 A+B landed); pre-read B-lo(buf0=T2).
    stageB(1, 1, kt3); VMC4(); ldBlo(0, bloA);
    BARRIER(); mmaH(bhi, 1, 1); BARRIER();
  }
  VMC0();   // drain wrapped garbage loads before LDS dealloc

  const int rowb = brow + wm * 128 + hi * 4;
  const int colb = bcol + wn * 64 + lr;

  if (EPI == 2) {
    unsigned short* C = (unsigned short*)Cv + cbase;
#pragma unroll
    for (int m = 0; m < 8; ++m) {
#pragma unroll
      for (int r = 0; r < 4; ++r) {
        float v0 = acc[m][0][r], v1 = acc[m][1][r], v2 = acc[m][2][r], v3 = acc[m][3][r];
        float mx = fmaxf(fmaxf(v0, v1), fmaxf(v2, v3));
        mx = fmaxf(mx, __shfl_xor(mx, 1));
        mx = fmaxf(mx, __shfl_xor(mx, 2));
        mx = fmaxf(mx, __shfl_xor(mx, 4));
        mx = fmaxf(mx, __shfl_xor(mx, 8));
        float e0 = __expf(v0 - mx), e1 = __expf(v1 - mx);
        float e2 = __expf(v2 - mx), e3 = __expf(v3 - mx);
        float s = e0 + e1 + e2 + e3;
        s += __shfl_xor(s, 1);
        s += __shfl_xor(s, 2);
        s += __shfl_xor(s, 4);
        s += __shfl_xor(s, 8);
        float inv = 1.0f / s;
        unsigned short* cp = C + (long)(rowb + m * 16 + r) * ldcL + colb;
        cp[0]  = f2b(e0 * inv);
        cp[16] = f2b(e1 * inv);
        cp[32] = f2b(e2 * inv);
        cp[48] = f2b(e3 * inv);
      }
    }
  } else {
    float* C = (float*)Cv + cbase;
#pragma unroll
    for (int n = 0; n < 4; ++n) {
      const int col = colb + n * 16;
      const float bv = bias[col];
#pragma unroll
      for (int m = 0; m < 8; ++m)
#pragma unroll
        for (int r = 0; r < 4; ++r)
          C[(long)(rowb + m * 16 + r) * ldcL + col] = acc[m][n][r] + bv;
    }
  }
}

extern "C" void kernel_launch(void* const* d_in, const int* in_sizes, int n_in,
                              void* d_out, int out_size, void* d_ws, size_t ws_size,
                              hipStream_t stream) {
  (void)in_sizes; (void)n_in; (void)out_size; (void)ws_size;
  const float* x0 = (const float*)d_in[0];
  const float* x2 = (const float*)d_in[1];
  const float* Wk = (const float*)d_in[2];
  const float* Wp = (const float*)d_in[3];
  const float* Wo = (const float*)d_in[4];
  const float* bo = (const float*)d_in[5];
  float* out = (float*)d_out;

  const long Bz = 8, Nn = 4096, Gg = 64, Dd = 1024;
  const long MN = Bz * Nn;  // 32768

  char* ws = (char*)d_ws;
  size_t off = 0;
  auto alloc = [&](size_t bytes) {
    size_t cur = off;
    off = (cur + bytes + 255) & ~(size_t)255;
    return (unsigned short*)(ws + cur);
  };
  unsigned short* x2b = alloc(MN * Dd * 2);       // 67 MB
  unsigned short* kb  = alloc(MN * Dd * 2);       // 67 MB
  unsigned short* Wkb = alloc(Dd * Dd * 2);
  unsigned short* Wpb = alloc(Dd * Dd * 2);
  unsigned short* Wob = alloc(Dd * Dd * 2);
  unsigned short* x0b = alloc(Bz * Gg * Dd * 2);
  unsigned short* Qtb = alloc(Bz * Dd * Dd * 2);  // 16.8 MB

  (void)hipFuncSetAttribute(reinterpret_cast<const void*>(gemm256<2, 0>),
                            hipFuncAttributeMaxDynamicSharedMemorySize, 131072);
  (void)hipFuncSetAttribute(reinterpret_cast<const void*>(gemm256<1, 1>),
                            hipFuncAttributeMaxDynamicSharedMemorySize, 131072);

  // Single cvt pass over all five f32 inputs.
  cvt_all<<<dim3(4096), dim3(256), 0, stream>>>(
      x2, x2b, (int)(MN * Dd / 4),
      x0, x0b, (int)(Bz * Gg * Dd / 4),
      Wk, Wkb, (int)(Dd * Dd / 4),
      Wp, Wpb, (int)(Dd * Dd / 4),
      Wo, Wob, (int)(Dd * Dd / 4));

  // GEMM1: kb = softmax_per_head(x2b @ Wkb^T), 512 blocks.
  gemm256<2, 0><<<dim3(512, 1, 1), dim3(512), 131072, stream>>>(
      x2b, Wkb, kb, nullptr, 1024, 0, 0, 0);

  // Fused P+Qt.
  qtp<<<dim3(4, 1, 128), dim3(256), 0, stream>>>(x0b, Wpb, Wob, Qtb);

  // out[b] = kb[b] @ Qtb[b]^T + bo, one batch per XCD.
  gemm256<1, 1><<<dim3(512, 1, 1), dim3(512), 131072, stream>>>(
      kb, Qtb, (void*)out, bo, 1024,
      (long)4096 * 1024, (long)1024 * 1024, (long)4096 * 1024);
}